// Round 19
// baseline (604.314 us; speedup 1.0000x reference)
//
#include <hip/hip_runtime.h>
#include <math.h>

#define N_NODES 50000
#define N_EDGES 800000
#define EPSV 1e-5f
#define PROJ_NT 16   // 16 nodes/block -> 3126 blocks: latency hiding (R5 win)
#define SCAN_NB ((N_NODES + 255) / 256)   // 196

// manual RNE float->bf16 (finite inputs only)
__device__ __forceinline__ unsigned short f2bf(float f) {
    unsigned u = __float_as_uint(f);
    unsigned r = (u + 0x7fffu + ((u >> 16) & 1u)) >> 16;
    return (unsigned short)r;
}
__device__ __forceinline__ float bflo(unsigned u) { return __uint_as_float(u << 16); }
__device__ __forceinline__ float bfhi(unsigned u) { return __uint_as_float(u & 0xffff0000u); }

// ---------------- CSR build ----------------

// counts per dst AND each edge's rank within its dst (atomicAdd return),
// so the scatter below needs no atomic (R18 win: 46us -> off top-5).
__global__ __launch_bounds__(256) void count_kernel(const int* __restrict__ dst,
                                                    int* __restrict__ cnt,
                                                    unsigned short* __restrict__ rank) {
    int e = blockIdx.x * 256 + threadIdx.x;
    if (e < N_EDGES) rank[e] = (unsigned short)atomicAdd(&cnt[dst[e]], 1);
}

__global__ __launch_bounds__(256) void scan_blocksum(const int* __restrict__ cnt,
                                                     int* __restrict__ bsum) {
    __shared__ int red[256];
    int t = threadIdx.x;
    int i = blockIdx.x * 256 + t;
    red[t] = (i < N_NODES) ? cnt[i] : 0;
    __syncthreads();
#pragma unroll
    for (int o = 128; o > 0; o >>= 1) {
        if (t < o) red[t] += red[t + o];
        __syncthreads();
    }
    if (t == 0) bsum[blockIdx.x] = red[0];
}

__global__ __launch_bounds__(256) void scan_bsum(int* __restrict__ bsum) {
    __shared__ int buf[256];
    int t = threadIdx.x;
    int v = (t < SCAN_NB) ? bsum[t] : 0;
    buf[t] = v;
    __syncthreads();
#pragma unroll
    for (int o = 1; o < 256; o <<= 1) {
        int tv = (t >= o) ? buf[t - o] : 0;
        __syncthreads();
        buf[t] += tv;
        __syncthreads();
    }
    if (t < SCAN_NB) bsum[t] = buf[t] - v;
}

__global__ __launch_bounds__(256) void scan_final(const int* __restrict__ cnt,
                                                  const int* __restrict__ bsum,
                                                  int* __restrict__ row_off) {
    __shared__ int buf[256];
    int t = threadIdx.x;
    int i = blockIdx.x * 256 + t;
    int v = (i < N_NODES) ? cnt[i] : 0;
    buf[t] = v;
    __syncthreads();
#pragma unroll
    for (int o = 1; o < 256; o <<= 1) {
        int tv = (t >= o) ? buf[t - o] : 0;
        __syncthreads();
        buf[t] += tv;
        __syncthreads();
    }
    int excl = buf[t] - v + bsum[blockIdx.x];
    if (i < N_NODES) row_off[i] = excl;
    if (i == N_NODES) row_off[N_NODES] = N_EDGES;
}

// atomic-FREE scatter: p = row_off[dst] + rank (R18 win)
__global__ __launch_bounds__(256) void scatter_kernel(const int* __restrict__ src,
                                                      const int* __restrict__ dst,
                                                      const unsigned short* __restrict__ rank,
                                                      const int* __restrict__ row_off,
                                                      unsigned short* __restrict__ ssrc) {
    int e = blockIdx.x * 256 + threadIdx.x;
    if (e < N_EDGES) {
        int p = row_off[dst[e]] + (int)rank[e];
        ssrc[p] = (unsigned short)src[e];
    }
}

// sdst in CSR order = node id repeated count[n] times: no scatter needed.
__global__ __launch_bounds__(256) void fill_dst_kernel(const int* __restrict__ row_off,
                                                       unsigned short* __restrict__ sdst) {
    int n = blockIdx.x * 256 + threadIdx.x;
    if (n >= N_NODES) return;
    int b = row_off[n], e2 = row_off[n + 1];
    for (int p = b; p < e2; ++p) sdst[p] = (unsigned short)n;
}

// ---- degree-sorted node order (kills agg wave-divergence: cntm = max of 8
//      Poisson(16) groups ~25 vs mean 16 -> ~35% wasted gather iterations) ----
__global__ __launch_bounds__(256) void deg_hist_kernel(const int* __restrict__ row_off,
                                                       int* __restrict__ hist) {
    int n = blockIdx.x * 256 + threadIdx.x;
    if (n < N_NODES) {
        int d = row_off[n + 1] - row_off[n];
        d = d > 127 ? 127 : d;
        atomicAdd(&hist[d], 1);
    }
}

__global__ void deg_scan_kernel(int* __restrict__ hist) {   // 128 threads
    __shared__ int sh[128];
    int t = threadIdx.x;
    int v = hist[t];
    sh[t] = v;
    __syncthreads();
#pragma unroll
    for (int o = 1; o < 128; o <<= 1) {
        int u = (t >= o) ? sh[t - o] : 0;
        __syncthreads();
        sh[t] += u;
        __syncthreads();
    }
    hist[t] = sh[t] - v;   // exclusive cursor per degree bin
}

__global__ __launch_bounds__(256) void deg_scatter_kernel(const int* __restrict__ row_off,
                                                          int* __restrict__ hist,
                                                          unsigned short* __restrict__ order) {
    int n = blockIdx.x * 256 + threadIdx.x;
    if (n < N_NODES) {
        int d = row_off[n + 1] - row_off[n];
        d = d > 127 ? 127 : d;
        int p = atomicAdd(&hist[d], 1);
        order[p] = (unsigned short)n;
    }
}

// ---------------- projections (+ fused BN/ReLU on input) ----------------
// R5-proven structure: wave m in {q,k,v,skip}. k,v -> planar bf16 rows.
template<bool BN>
__global__ __launch_bounds__(256) void proj_kernel(
    const float* __restrict__ hin,
    const float* __restrict__ Wq, const float* __restrict__ Wk,
    const float* __restrict__ Wv, const float* __restrict__ Ws,
    const float* __restrict__ bq, const float* __restrict__ bk,
    const float* __restrict__ bv, const float* __restrict__ bs,
    const float* __restrict__ bnp, const float* __restrict__ gamma,
    const float* __restrict__ beta,
    float* __restrict__ qb, unsigned short* __restrict__ kb,
    unsigned short* __restrict__ vb, float* __restrict__ skb)
{
    __shared__ float xs[16][64];
    const int t = threadIdx.x;
    const int m = t >> 6, c = t & 63;
    const float* Wm = (m == 0) ? Wq : (m == 1) ? Wk : (m == 2) ? Wv : Ws;
    const float* bm = (m == 0) ? bq : (m == 1) ? bk : (m == 2) ? bv : bs;
    float*          obase_f = ((m == 0) ? qb : skb) + c;        // m 0/3
    unsigned short* obase_h = ((m == 1) ? kb : vb) + c;         // m 1/2

    float w[64];
#pragma unroll
    for (int i = 0; i < 64; i++) w[i] = Wm[i * 64 + c];
    const float bias = bm[c];

    const int jj = t >> 4, i0 = (t & 15) * 4;
    float4 mu4, rs4, ga4, be4;
    if (BN) {
        mu4 = *(const float4*)&bnp[i0];
        rs4 = *(const float4*)&bnp[64 + i0];
        ga4 = *(const float4*)&gamma[i0];
        be4 = *(const float4*)&beta[i0];
    }

    const int nbase = blockIdx.x * PROJ_NT;
    for (int tile = 0; tile < PROJ_NT / 16; ++tile) {
        const int n0 = nbase + tile * 16;
        __syncthreads();
        {
            int node = n0 + jj;
            float4 xv = make_float4(0.f, 0.f, 0.f, 0.f);
            if (node < N_NODES) xv = *(const float4*)&hin[node * 64 + i0];
            if (BN) {
                xv.x = fmaxf(fmaf(ga4.x * (xv.x - mu4.x), rs4.x, be4.x), 0.f);
                xv.y = fmaxf(fmaf(ga4.y * (xv.y - mu4.y), rs4.y, be4.y), 0.f);
                xv.z = fmaxf(fmaf(ga4.z * (xv.z - mu4.z), rs4.z, be4.z), 0.f);
                xv.w = fmaxf(fmaf(ga4.w * (xv.w - mu4.w), rs4.w, be4.w), 0.f);
            }
            *(float4*)&xs[jj][i0] = xv;
        }
        __syncthreads();
#pragma unroll 4
        for (int j = 0; j < 16; j++) {
            const int node = n0 + j;
            if (node >= N_NODES) break;   // uniform across block
            float a0 = bias, a1 = 0.f, a2 = 0.f, a3 = 0.f;
#pragma unroll
            for (int i4 = 0; i4 < 16; i4++) {
                float4 xv = *(const float4*)&xs[j][i4 * 4];
                a0 = fmaf(xv.x, w[i4 * 4 + 0], a0);
                a1 = fmaf(xv.y, w[i4 * 4 + 1], a1);
                a2 = fmaf(xv.z, w[i4 * 4 + 2], a2);
                a3 = fmaf(xv.w, w[i4 * 4 + 3], a3);
            }
            float r = (a0 + a1) + (a2 + a3);
            if (m == 0 || m == 3) obase_f[(size_t)node * 64] = r;
            else                  obase_h[(size_t)node * 64] = f2bf(r);
        }
    }
}

// ---------------- edge scores (edge-parallel, 8 lanes/edge) ----------------
__global__ __launch_bounds__(256) void edge_kernel(const float* __restrict__ qb,
                                                   const unsigned short* __restrict__ kb,
                                                   const unsigned short* __restrict__ ssrc,
                                                   const unsigned short* __restrict__ sdst,
                                                   float* __restrict__ s_out) {
    int idx = blockIdx.x * 256 + threadIdx.x;
    int e   = idx >> 3;
    int l8  = idx & 7;
    if (e >= N_EDGES) return;
    int s = ssrc[e], d = sdst[e];
    const float4* qp = (const float4*)&qb[(size_t)d * 64 + l8 * 8];
    float4 q0 = qp[0], q1 = qp[1];
    uint4 kw = *(const uint4*)&kb[(size_t)s * 64 + l8 * 8];
    float acc = q0.x * bflo(kw.x) + q0.y * bfhi(kw.x)
              + q0.z * bflo(kw.y) + q0.w * bfhi(kw.y)
              + q1.x * bflo(kw.z) + q1.y * bfhi(kw.z)
              + q1.z * bflo(kw.w) + q1.w * bfhi(kw.w);
    acc += __shfl_xor(acc, 1);
    acc += __shfl_xor(acc, 2);
    acc += __shfl_xor(acc, 4);
    if (l8 == 0) s_out[e] = acc * 0.125f;   // 1/sqrt(64)
}

// ---------------- softmax + weighted aggregation ----------------
// 8-lane group per node (8 nodes/wave), nodes in DEGREE-SORTED order so the
// wave-uniform bound cntm ~= every group's degree (no drained-group waste).
__global__ __launch_bounds__(256) void agg_kernel(const float* __restrict__ s_arr,
                                                  const unsigned short* __restrict__ vb,
                                                  const unsigned short* __restrict__ ssrc,
                                                  const int* __restrict__ row_off,
                                                  const unsigned short* __restrict__ order,
                                                  const float* __restrict__ skb,
                                                  float* __restrict__ out) {
    int tid  = blockIdx.x * 256 + threadIdx.x;
    int lane = threadIdx.x & 63;
    int l8   = lane & 7;
    int gslot = (tid >> 6) * 8 + (lane >> 3);
    bool valid = gslot < N_NODES;
    int g = 0;
    int beg = 0, end = 0;
    float4 sk0 = make_float4(0, 0, 0, 0), sk1 = sk0;
    if (valid) {
        g   = (int)order[gslot];
        beg = row_off[g];
        end = row_off[g + 1];
        const float4* skp = (const float4*)&skb[(size_t)g * 64 + l8 * 8];
        sk0 = skp[0];
        sk1 = skp[1];
    }

    float mx = -INFINITY;
    for (int p = beg + l8; p < end; p += 8) mx = fmaxf(mx, s_arr[p]);
    mx = fmaxf(mx, __shfl_xor(mx, 1));
    mx = fmaxf(mx, __shfl_xor(mx, 2));
    mx = fmaxf(mx, __shfl_xor(mx, 4));

    const uint4* vw = (const uint4*)vb;
    const int sbase = lane & 56;              // group base lane
    float lsum = 0.f;
    float a0 = 0, a1 = 0, a2 = 0, a3 = 0, a4 = 0, a5 = 0, a6 = 0, a7 = 0;
    int base = beg;
    while (true) {
        int cnt = end - base;
        cnt = cnt < 0 ? 0 : (cnt > 16 ? 16 : cnt);
        int c = max(cnt, __shfl_xor(cnt, 8));
        c = max(c, __shfl_xor(c, 16));
        int cntm = max(c, __shfl_xor(c, 32));  // wave-uniform bound (<=16)
        if (cntm == 0) break;
        float e0 = 0.f, e1 = 0.f;
        int   s0 = 0,   s1 = 0;
        if (l8 < cnt) {
            e0 = __expf(s_arr[base + l8] - mx);
            s0 = (int)ssrc[base + l8];
        }
        if (l8 + 8 < cnt) {
            e1 = __expf(s_arr[base + 8 + l8] - mx);
            s1 = (int)ssrc[base + 8 + l8];
        }
        lsum += e0 + e1;
        int n0 = cntm < 8 ? cntm : 8;
        int n1 = cntm - 8; n1 = n1 < 0 ? 0 : n1;
#pragma unroll 2
        for (int j = 0; j < n0; ++j) {
            float w  = __shfl(e0, sbase + j);
            int   sv = __shfl(s0, sbase + j);
            uint4 vv = vw[(size_t)sv * 8 + l8];
            a0 = fmaf(w, bflo(vv.x), a0); a1 = fmaf(w, bfhi(vv.x), a1);
            a2 = fmaf(w, bflo(vv.y), a2); a3 = fmaf(w, bfhi(vv.y), a3);
            a4 = fmaf(w, bflo(vv.z), a4); a5 = fmaf(w, bfhi(vv.z), a5);
            a6 = fmaf(w, bflo(vv.w), a6); a7 = fmaf(w, bfhi(vv.w), a7);
        }
#pragma unroll 2
        for (int j = 0; j < n1; ++j) {
            float w  = __shfl(e1, sbase + j);
            int   sv = __shfl(s1, sbase + j);
            uint4 vv = vw[(size_t)sv * 8 + l8];
            a0 = fmaf(w, bflo(vv.x), a0); a1 = fmaf(w, bfhi(vv.x), a1);
            a2 = fmaf(w, bflo(vv.y), a2); a3 = fmaf(w, bfhi(vv.y), a3);
            a4 = fmaf(w, bflo(vv.z), a4); a5 = fmaf(w, bfhi(vv.z), a5);
            a6 = fmaf(w, bflo(vv.w), a6); a7 = fmaf(w, bfhi(vv.w), a7);
        }
        base += 16;
    }
    lsum += __shfl_xor(lsum, 1);
    lsum += __shfl_xor(lsum, 2);
    lsum += __shfl_xor(lsum, 4);
    if (valid) {
        float inv = (end > beg) ? 1.f / lsum : 0.f;
        float4 r0, r1;
        r0.x = fmaf(a0, inv, sk0.x); r0.y = fmaf(a1, inv, sk0.y);
        r0.z = fmaf(a2, inv, sk0.z); r0.w = fmaf(a3, inv, sk0.w);
        r1.x = fmaf(a4, inv, sk1.x); r1.y = fmaf(a5, inv, sk1.y);
        r1.z = fmaf(a6, inv, sk1.z); r1.w = fmaf(a7, inv, sk1.w);
        float4* op = (float4*)&out[(size_t)g * 64 + l8 * 8];
        op[0] = r0;
        op[1] = r1;
    }
}

// ---------------- batchnorm: per-block partials (no atomics, no memset) ----
__global__ __launch_bounds__(256) void bn_stats_kernel(const float* __restrict__ h,
                                                       float* __restrict__ partials) {
    __shared__ float red[256], red2[256];
    int t = threadIdx.x;
    int d = t & 63, part = t >> 6;
    float s = 0.f, s2 = 0.f;
    for (int r = blockIdx.x * 4 + part; r < N_NODES; r += gridDim.x * 4) {
        float v = h[r * 64 + d];
        s += v;
        s2 = fmaf(v, v, s2);
    }
    red[t] = s; red2[t] = s2;
    __syncthreads();
    if (t < 64) {
        s  = red[t] + red[t + 64] + red[t + 128] + red[t + 192];
        s2 = red2[t] + red2[t + 64] + red2[t + 128] + red2[t + 192];
        partials[blockIdx.x * 128 + t]      = s;
        partials[blockIdx.x * 128 + 64 + t] = s2;
    }
}

__global__ void bn_final_kernel(const float* __restrict__ partials,
                                float* __restrict__ bnp) {
    __shared__ float sh[128];
    int t = threadIdx.x;   // 128 threads
    float a = 0.f;
    for (int b = 0; b < 256; ++b) a += partials[b * 128 + t];
    sh[t] = a;
    __syncthreads();
    if (t < 64) {
        float mean = sh[t] * (1.0f / N_NODES);
        float var  = sh[64 + t] * (1.0f / N_NODES) - mean * mean;
        bnp[t]      = mean;
        bnp[64 + t] = rsqrtf(var + EPSV);
    }
}

// ---------------- launch ----------------

extern "C" void kernel_launch(void* const* d_in, const int* in_sizes, int n_in,
                              void* d_out, int out_size, void* d_ws, size_t ws_size,
                              hipStream_t stream) {
    const float* x     = (const float*)d_in[0];
    const int*   ei    = (const int*)d_in[1];
    const float* Wq    = (const float*)d_in[2];
    const float* bq    = (const float*)d_in[3];
    const float* Wk    = (const float*)d_in[4];
    const float* bk    = (const float*)d_in[5];
    const float* Wv    = (const float*)d_in[6];
    const float* bv    = (const float*)d_in[7];
    const float* Ws    = (const float*)d_in[8];
    const float* bs    = (const float*)d_in[9];
    const float* gamma = (const float*)d_in[10];
    const float* beta  = (const float*)d_in[11];
    float* out = (float*)d_out;

    char* wsp = (char*)d_ws;
    size_t off = 0;
    auto alloc = [&](size_t bytes) -> void* {
        void* p = wsp + off;
        off += (bytes + 255) / 256 * 256;
        return p;
    };
    float*          qb       = (float*)alloc((size_t)N_NODES * 64 * 4);
    unsigned short* kb       = (unsigned short*)alloc((size_t)N_NODES * 64 * 2);
    unsigned short* vb       = (unsigned short*)alloc((size_t)N_NODES * 64 * 2);
    float*          skb      = (float*)alloc((size_t)N_NODES * 64 * 4);
    float*          hbuf     = (float*)alloc((size_t)N_NODES * 64 * 4);
    float*          s_arr    = (float*)alloc((size_t)N_EDGES * 4);
    int*            row_off  = (int*)alloc((size_t)(N_NODES + 1) * 4);
    int*            cnt      = (int*)alloc((size_t)N_NODES * 4);
    unsigned short* ssrc     = (unsigned short*)alloc((size_t)N_EDGES * 2);
    unsigned short* sdst     = (unsigned short*)alloc((size_t)N_EDGES * 2);
    unsigned short* rank     = (unsigned short*)alloc((size_t)N_EDGES * 2);
    unsigned short* order    = (unsigned short*)alloc((size_t)N_NODES * 2);
    int*            bsum     = (int*)alloc((size_t)SCAN_NB * 4);
    int*            hist     = (int*)alloc(128 * 4);
    float*          partials = (float*)alloc(256 * 128 * 4);
    float*          bnp      = (float*)alloc(128 * 4);

    const int* src = ei;
    const int* dst = ei + N_EDGES;

    // CSR build (edge_index is layer-invariant)
    hipMemsetAsync(cnt, 0, N_NODES * 4, stream);
    hipMemsetAsync(hist, 0, 128 * 4, stream);
    count_kernel<<<(N_EDGES + 255) / 256, 256, 0, stream>>>(dst, cnt, rank);
    scan_blocksum<<<SCAN_NB, 256, 0, stream>>>(cnt, bsum);
    scan_bsum<<<1, 256, 0, stream>>>(bsum);
    scan_final<<<SCAN_NB, 256, 0, stream>>>(cnt, bsum, row_off);
    scatter_kernel<<<(N_EDGES + 255) / 256, 256, 0, stream>>>(src, dst, rank, row_off, ssrc);
    fill_dst_kernel<<<SCAN_NB, 256, 0, stream>>>(row_off, sdst);
    // degree-sorted node order for agg
    deg_hist_kernel<<<SCAN_NB, 256, 0, stream>>>(row_off, hist);
    deg_scan_kernel<<<1, 128, 0, stream>>>(hist);
    deg_scatter_kernel<<<SCAN_NB, 256, 0, stream>>>(row_off, hist, order);

    const int proj_grid = (N_NODES + PROJ_NT - 1) / PROJ_NT;   // 3126
    const int edge_grid = (N_EDGES * 8 + 255) / 256;           // 25000
    const int agg_grid  = (N_NODES + 31) / 32;                 // 1563

    for (int l = 0; l < 3; l++) {
        const float* hin = (l == 0) ? x : hbuf;
        if (l == 0) {
            proj_kernel<false><<<proj_grid, 256, 0, stream>>>(
                hin, Wq, Wk, Wv, Ws, bq, bk, bv, bs,
                bnp, gamma, beta, qb, kb, vb, skb);
        } else {
            proj_kernel<true><<<proj_grid, 256, 0, stream>>>(
                hin, Wq + l * 4096, Wk + l * 4096, Wv + l * 4096, Ws + l * 4096,
                bq + l * 64, bk + l * 64, bv + l * 64, bs + l * 64,
                bnp, gamma + (l - 1) * 64, beta + (l - 1) * 64, qb, kb, vb, skb);
        }
        edge_kernel<<<edge_grid, 256, 0, stream>>>(qb, kb, ssrc, sdst, s_arr);
        float* o = (l == 2) ? out : hbuf;
        agg_kernel<<<agg_grid, 256, 0, stream>>>(s_arr, vb, ssrc, row_off, order, skb, o);
        if (l < 2) {
            bn_stats_kernel<<<256, 256, 0, stream>>>(hbuf, partials);
            bn_final_kernel<<<1, 128, 0, stream>>>(partials, bnp);
        }
    }
}

// Round 20
// 324.316 us; speedup vs baseline: 1.8633x; 1.8633x over previous
//
#include <hip/hip_runtime.h>
#include <math.h>

#define N_NODES 50000
#define N_EDGES 800000
#define EPSV 1e-5f
#define PROJ_NT 16   // 16 nodes/block -> 3126 blocks: latency hiding (R5 win)
#define SCAN_NB ((N_NODES + 255) / 256)   // 196

// manual RNE float->bf16 (finite inputs only)
__device__ __forceinline__ unsigned short f2bf(float f) {
    unsigned u = __float_as_uint(f);
    unsigned r = (u + 0x7fffu + ((u >> 16) & 1u)) >> 16;
    return (unsigned short)r;
}
__device__ __forceinline__ float bflo(unsigned u) { return __uint_as_float(u << 16); }
__device__ __forceinline__ float bfhi(unsigned u) { return __uint_as_float(u & 0xffff0000u); }

// ---------------- CSR build ----------------

// counts per dst AND each edge's rank within its dst (atomicAdd return),
// so the scatter below needs no atomic (R18 win: 46us -> off top-5).
__global__ __launch_bounds__(256) void count_kernel(const int* __restrict__ dst,
                                                    int* __restrict__ cnt,
                                                    unsigned short* __restrict__ rank) {
    int e = blockIdx.x * 256 + threadIdx.x;
    if (e < N_EDGES) rank[e] = (unsigned short)atomicAdd(&cnt[dst[e]], 1);
}

__global__ __launch_bounds__(256) void scan_blocksum(const int* __restrict__ cnt,
                                                     int* __restrict__ bsum) {
    __shared__ int red[256];
    int t = threadIdx.x;
    int i = blockIdx.x * 256 + t;
    red[t] = (i < N_NODES) ? cnt[i] : 0;
    __syncthreads();
#pragma unroll
    for (int o = 128; o > 0; o >>= 1) {
        if (t < o) red[t] += red[t + o];
        __syncthreads();
    }
    if (t == 0) bsum[blockIdx.x] = red[0];
}

__global__ __launch_bounds__(256) void scan_bsum(int* __restrict__ bsum) {
    __shared__ int buf[256];
    int t = threadIdx.x;
    int v = (t < SCAN_NB) ? bsum[t] : 0;
    buf[t] = v;
    __syncthreads();
#pragma unroll
    for (int o = 1; o < 256; o <<= 1) {
        int tv = (t >= o) ? buf[t - o] : 0;
        __syncthreads();
        buf[t] += tv;
        __syncthreads();
    }
    if (t < SCAN_NB) bsum[t] = buf[t] - v;
}

__global__ __launch_bounds__(256) void scan_final(const int* __restrict__ cnt,
                                                  const int* __restrict__ bsum,
                                                  int* __restrict__ row_off) {
    __shared__ int buf[256];
    int t = threadIdx.x;
    int i = blockIdx.x * 256 + t;
    int v = (i < N_NODES) ? cnt[i] : 0;
    buf[t] = v;
    __syncthreads();
#pragma unroll
    for (int o = 1; o < 256; o <<= 1) {
        int tv = (t >= o) ? buf[t - o] : 0;
        __syncthreads();
        buf[t] += tv;
        __syncthreads();
    }
    int excl = buf[t] - v + bsum[blockIdx.x];
    if (i < N_NODES) row_off[i] = excl;
    if (i == N_NODES) row_off[N_NODES] = N_EDGES;
}

// atomic-FREE scatter: p = row_off[dst] + rank (R18 win)
__global__ __launch_bounds__(256) void scatter_kernel(const int* __restrict__ src,
                                                      const int* __restrict__ dst,
                                                      const unsigned short* __restrict__ rank,
                                                      const int* __restrict__ row_off,
                                                      unsigned short* __restrict__ ssrc) {
    int e = blockIdx.x * 256 + threadIdx.x;
    if (e < N_EDGES) {
        int p = row_off[dst[e]] + (int)rank[e];
        ssrc[p] = (unsigned short)src[e];
    }
}

// sdst in CSR order = node id repeated count[n] times: no scatter needed.
__global__ __launch_bounds__(256) void fill_dst_kernel(const int* __restrict__ row_off,
                                                       unsigned short* __restrict__ sdst) {
    int n = blockIdx.x * 256 + threadIdx.x;
    if (n >= N_NODES) return;
    int b = row_off[n], e2 = row_off[n + 1];
    for (int p = b; p < e2; ++p) sdst[p] = (unsigned short)n;
}

// ---------------- projections (+ fused BN/ReLU on input) ----------------
// R5-proven structure: wave m in {q,k,v,skip}. k,v -> planar bf16 rows.
template<bool BN>
__global__ __launch_bounds__(256) void proj_kernel(
    const float* __restrict__ hin,
    const float* __restrict__ Wq, const float* __restrict__ Wk,
    const float* __restrict__ Wv, const float* __restrict__ Ws,
    const float* __restrict__ bq, const float* __restrict__ bk,
    const float* __restrict__ bv, const float* __restrict__ bs,
    const float* __restrict__ bnp, const float* __restrict__ gamma,
    const float* __restrict__ beta,
    float* __restrict__ qb, unsigned short* __restrict__ kb,
    unsigned short* __restrict__ vb, float* __restrict__ skb)
{
    __shared__ float xs[16][64];
    const int t = threadIdx.x;
    const int m = t >> 6, c = t & 63;
    const float* Wm = (m == 0) ? Wq : (m == 1) ? Wk : (m == 2) ? Wv : Ws;
    const float* bm = (m == 0) ? bq : (m == 1) ? bk : (m == 2) ? bv : bs;
    float*          obase_f = ((m == 0) ? qb : skb) + c;        // m 0/3
    unsigned short* obase_h = ((m == 1) ? kb : vb) + c;         // m 1/2

    float w[64];
#pragma unroll
    for (int i = 0; i < 64; i++) w[i] = Wm[i * 64 + c];
    const float bias = bm[c];

    const int jj = t >> 4, i0 = (t & 15) * 4;
    float4 mu4, rs4, ga4, be4;
    if (BN) {
        mu4 = *(const float4*)&bnp[i0];
        rs4 = *(const float4*)&bnp[64 + i0];
        ga4 = *(const float4*)&gamma[i0];
        be4 = *(const float4*)&beta[i0];
    }

    const int nbase = blockIdx.x * PROJ_NT;
    for (int tile = 0; tile < PROJ_NT / 16; ++tile) {
        const int n0 = nbase + tile * 16;
        __syncthreads();
        {
            int node = n0 + jj;
            float4 xv = make_float4(0.f, 0.f, 0.f, 0.f);
            if (node < N_NODES) xv = *(const float4*)&hin[node * 64 + i0];
            if (BN) {
                xv.x = fmaxf(fmaf(ga4.x * (xv.x - mu4.x), rs4.x, be4.x), 0.f);
                xv.y = fmaxf(fmaf(ga4.y * (xv.y - mu4.y), rs4.y, be4.y), 0.f);
                xv.z = fmaxf(fmaf(ga4.z * (xv.z - mu4.z), rs4.z, be4.z), 0.f);
                xv.w = fmaxf(fmaf(ga4.w * (xv.w - mu4.w), rs4.w, be4.w), 0.f);
            }
            *(float4*)&xs[jj][i0] = xv;
        }
        __syncthreads();
#pragma unroll 4
        for (int j = 0; j < 16; j++) {
            const int node = n0 + j;
            if (node >= N_NODES) break;   // uniform across block
            float a0 = bias, a1 = 0.f, a2 = 0.f, a3 = 0.f;
#pragma unroll
            for (int i4 = 0; i4 < 16; i4++) {
                float4 xv = *(const float4*)&xs[j][i4 * 4];
                a0 = fmaf(xv.x, w[i4 * 4 + 0], a0);
                a1 = fmaf(xv.y, w[i4 * 4 + 1], a1);
                a2 = fmaf(xv.z, w[i4 * 4 + 2], a2);
                a3 = fmaf(xv.w, w[i4 * 4 + 3], a3);
            }
            float r = (a0 + a1) + (a2 + a3);
            if (m == 0 || m == 3) obase_f[(size_t)node * 64] = r;
            else                  obase_h[(size_t)node * 64] = f2bf(r);
        }
    }
}

// ---------------- edge scores (edge-parallel, 8 lanes/edge) ----------------
__global__ __launch_bounds__(256) void edge_kernel(const float* __restrict__ qb,
                                                   const unsigned short* __restrict__ kb,
                                                   const unsigned short* __restrict__ ssrc,
                                                   const unsigned short* __restrict__ sdst,
                                                   float* __restrict__ s_out) {
    int idx = blockIdx.x * 256 + threadIdx.x;
    int e   = idx >> 3;
    int l8  = idx & 7;
    if (e >= N_EDGES) return;
    int s = ssrc[e], d = sdst[e];
    const float4* qp = (const float4*)&qb[(size_t)d * 64 + l8 * 8];
    float4 q0 = qp[0], q1 = qp[1];
    uint4 kw = *(const uint4*)&kb[(size_t)s * 64 + l8 * 8];
    float acc = q0.x * bflo(kw.x) + q0.y * bfhi(kw.x)
              + q0.z * bflo(kw.y) + q0.w * bfhi(kw.y)
              + q1.x * bflo(kw.z) + q1.y * bfhi(kw.z)
              + q1.z * bflo(kw.w) + q1.w * bfhi(kw.w);
    acc += __shfl_xor(acc, 1);
    acc += __shfl_xor(acc, 2);
    acc += __shfl_xor(acc, 4);
    if (l8 == 0) s_out[e] = acc * 0.125f;   // 1/sqrt(64)
}

// ---------------- softmax + weighted aggregation ----------------
// 8-lane group per node (8 nodes/wave), PER-GROUP loop bounds: all 8 lanes of
// a group share beg/end, and __shfl only sources within the group, so the
// cross-group wave-max bound (R8-R17) is unnecessary. Groups that drain are
// exec-masked off -> no dummy gathers/fmas for them (divergence waste:
// E[max of 8 Poisson(16)] ~ 25 vs mean 16).
__global__ __launch_bounds__(256) void agg_kernel(const float* __restrict__ s_arr,
                                                  const unsigned short* __restrict__ vb,
                                                  const unsigned short* __restrict__ ssrc,
                                                  const int* __restrict__ row_off,
                                                  const float* __restrict__ skb,
                                                  float* __restrict__ out) {
    int tid  = blockIdx.x * 256 + threadIdx.x;
    int lane = threadIdx.x & 63;
    int l8   = lane & 7;
    int g    = (tid >> 6) * 8 + (lane >> 3);
    bool valid = g < N_NODES;
    int beg = 0, end = 0;
    float4 sk0 = make_float4(0, 0, 0, 0), sk1 = sk0;
    if (valid) {
        beg = row_off[g];
        end = row_off[g + 1];
        const float4* skp = (const float4*)&skb[(size_t)g * 64 + l8 * 8];
        sk0 = skp[0];
        sk1 = skp[1];
    }

    float mx = -INFINITY;
    for (int p = beg + l8; p < end; p += 8) mx = fmaxf(mx, s_arr[p]);
    mx = fmaxf(mx, __shfl_xor(mx, 1));
    mx = fmaxf(mx, __shfl_xor(mx, 2));
    mx = fmaxf(mx, __shfl_xor(mx, 4));

    const uint4* vw = (const uint4*)vb;
    const int sbase = lane & 56;              // group base lane
    float lsum = 0.f;
    float a0 = 0, a1 = 0, a2 = 0, a3 = 0, a4 = 0, a5 = 0, a6 = 0, a7 = 0;
    int base = beg;
    while (base < end) {                      // per-group bound (divergent OK)
        int cnt = end - base;
        cnt = cnt > 16 ? 16 : cnt;
        float e0 = 0.f, e1 = 0.f;
        int   s0 = 0,   s1 = 0;
        if (l8 < cnt) {
            e0 = __expf(s_arr[base + l8] - mx);
            s0 = (int)ssrc[base + l8];
        }
        if (l8 + 8 < cnt) {
            e1 = __expf(s_arr[base + 8 + l8] - mx);
            s1 = (int)ssrc[base + 8 + l8];
        }
        lsum += e0 + e1;
        int n0 = cnt < 8 ? cnt : 8;
        int n1 = cnt - 8; n1 = n1 < 0 ? 0 : n1;
#pragma unroll 2
        for (int j = 0; j < n0; ++j) {
            float w  = __shfl(e0, sbase + j);
            int   sv = __shfl(s0, sbase + j);
            uint4 vv = vw[(size_t)sv * 8 + l8];
            a0 = fmaf(w, bflo(vv.x), a0); a1 = fmaf(w, bfhi(vv.x), a1);
            a2 = fmaf(w, bflo(vv.y), a2); a3 = fmaf(w, bfhi(vv.y), a3);
            a4 = fmaf(w, bflo(vv.z), a4); a5 = fmaf(w, bfhi(vv.z), a5);
            a6 = fmaf(w, bflo(vv.w), a6); a7 = fmaf(w, bfhi(vv.w), a7);
        }
#pragma unroll 2
        for (int j = 0; j < n1; ++j) {
            float w  = __shfl(e1, sbase + j);
            int   sv = __shfl(s1, sbase + j);
            uint4 vv = vw[(size_t)sv * 8 + l8];
            a0 = fmaf(w, bflo(vv.x), a0); a1 = fmaf(w, bfhi(vv.x), a1);
            a2 = fmaf(w, bflo(vv.y), a2); a3 = fmaf(w, bfhi(vv.y), a3);
            a4 = fmaf(w, bflo(vv.z), a4); a5 = fmaf(w, bfhi(vv.z), a5);
            a6 = fmaf(w, bflo(vv.w), a6); a7 = fmaf(w, bfhi(vv.w), a7);
        }
        base += 16;
    }
    lsum += __shfl_xor(lsum, 1);
    lsum += __shfl_xor(lsum, 2);
    lsum += __shfl_xor(lsum, 4);
    if (valid) {
        float inv = (end > beg) ? 1.f / lsum : 0.f;
        float4 r0, r1;
        r0.x = fmaf(a0, inv, sk0.x); r0.y = fmaf(a1, inv, sk0.y);
        r0.z = fmaf(a2, inv, sk0.z); r0.w = fmaf(a3, inv, sk0.w);
        r1.x = fmaf(a4, inv, sk1.x); r1.y = fmaf(a5, inv, sk1.y);
        r1.z = fmaf(a6, inv, sk1.z); r1.w = fmaf(a7, inv, sk1.w);
        float4* op = (float4*)&out[(size_t)g * 64 + l8 * 8];
        op[0] = r0;
        op[1] = r1;
    }
}

// ---------------- batchnorm: per-block partials (no atomics, no memset) ----
__global__ __launch_bounds__(256) void bn_stats_kernel(const float* __restrict__ h,
                                                       float* __restrict__ partials) {
    __shared__ float red[256], red2[256];
    int t = threadIdx.x;
    int d = t & 63, part = t >> 6;
    float s = 0.f, s2 = 0.f;
    for (int r = blockIdx.x * 4 + part; r < N_NODES; r += gridDim.x * 4) {
        float v = h[r * 64 + d];
        s += v;
        s2 = fmaf(v, v, s2);
    }
    red[t] = s; red2[t] = s2;
    __syncthreads();
    if (t < 64) {
        s  = red[t] + red[t + 64] + red[t + 128] + red[t + 192];
        s2 = red2[t] + red2[t + 64] + red2[t + 128] + red2[t + 192];
        partials[blockIdx.x * 128 + t]      = s;
        partials[blockIdx.x * 128 + 64 + t] = s2;
    }
}

__global__ void bn_final_kernel(const float* __restrict__ partials,
                                float* __restrict__ bnp) {
    __shared__ float sh[128];
    int t = threadIdx.x;   // 128 threads
    float a = 0.f;
    for (int b = 0; b < 256; ++b) a += partials[b * 128 + t];
    sh[t] = a;
    __syncthreads();
    if (t < 64) {
        float mean = sh[t] * (1.0f / N_NODES);
        float var  = sh[64 + t] * (1.0f / N_NODES) - mean * mean;
        bnp[t]      = mean;
        bnp[64 + t] = rsqrtf(var + EPSV);
    }
}

// ---------------- launch ----------------

extern "C" void kernel_launch(void* const* d_in, const int* in_sizes, int n_in,
                              void* d_out, int out_size, void* d_ws, size_t ws_size,
                              hipStream_t stream) {
    const float* x     = (const float*)d_in[0];
    const int*   ei    = (const int*)d_in[1];
    const float* Wq    = (const float*)d_in[2];
    const float* bq    = (const float*)d_in[3];
    const float* Wk    = (const float*)d_in[4];
    const float* bk    = (const float*)d_in[5];
    const float* Wv    = (const float*)d_in[6];
    const float* bv    = (const float*)d_in[7];
    const float* Ws    = (const float*)d_in[8];
    const float* bs    = (const float*)d_in[9];
    const float* gamma = (const float*)d_in[10];
    const float* beta  = (const float*)d_in[11];
    float* out = (float*)d_out;

    char* wsp = (char*)d_ws;
    size_t off = 0;
    auto alloc = [&](size_t bytes) -> void* {
        void* p = wsp + off;
        off += (bytes + 255) / 256 * 256;
        return p;
    };
    float*          qb       = (float*)alloc((size_t)N_NODES * 64 * 4);
    unsigned short* kb       = (unsigned short*)alloc((size_t)N_NODES * 64 * 2);
    unsigned short* vb       = (unsigned short*)alloc((size_t)N_NODES * 64 * 2);
    float*          skb      = (float*)alloc((size_t)N_NODES * 64 * 4);
    float*          hbuf     = (float*)alloc((size_t)N_NODES * 64 * 4);
    float*          s_arr    = (float*)alloc((size_t)N_EDGES * 4);
    int*            row_off  = (int*)alloc((size_t)(N_NODES + 1) * 4);
    int*            cnt      = (int*)alloc((size_t)N_NODES * 4);
    unsigned short* ssrc     = (unsigned short*)alloc((size_t)N_EDGES * 2);
    unsigned short* sdst     = (unsigned short*)alloc((size_t)N_EDGES * 2);
    unsigned short* rank     = (unsigned short*)alloc((size_t)N_EDGES * 2);
    int*            bsum     = (int*)alloc((size_t)SCAN_NB * 4);
    float*          partials = (float*)alloc(256 * 128 * 4);
    float*          bnp      = (float*)alloc(128 * 4);

    const int* src = ei;
    const int* dst = ei + N_EDGES;

    // CSR build (edge_index is layer-invariant)
    hipMemsetAsync(cnt, 0, N_NODES * 4, stream);
    count_kernel<<<(N_EDGES + 255) / 256, 256, 0, stream>>>(dst, cnt, rank);
    scan_blocksum<<<SCAN_NB, 256, 0, stream>>>(cnt, bsum);
    scan_bsum<<<1, 256, 0, stream>>>(bsum);
    scan_final<<<SCAN_NB, 256, 0, stream>>>(cnt, bsum, row_off);
    scatter_kernel<<<(N_EDGES + 255) / 256, 256, 0, stream>>>(src, dst, rank, row_off, ssrc);
    fill_dst_kernel<<<SCAN_NB, 256, 0, stream>>>(row_off, sdst);

    const int proj_grid = (N_NODES + PROJ_NT - 1) / PROJ_NT;   // 3126
    const int edge_grid = (N_EDGES * 8 + 255) / 256;           // 25000
    const int agg_grid  = (N_NODES + 31) / 32;                 // 1563

    for (int l = 0; l < 3; l++) {
        const float* hin = (l == 0) ? x : hbuf;
        if (l == 0) {
            proj_kernel<false><<<proj_grid, 256, 0, stream>>>(
                hin, Wq, Wk, Wv, Ws, bq, bk, bv, bs,
                bnp, gamma, beta, qb, kb, vb, skb);
        } else {
            proj_kernel<true><<<proj_grid, 256, 0, stream>>>(
                hin, Wq + l * 4096, Wk + l * 4096, Wv + l * 4096, Ws + l * 4096,
                bq + l * 64, bk + l * 64, bv + l * 64, bs + l * 64,
                bnp, gamma + (l - 1) * 64, beta + (l - 1) * 64, qb, kb, vb, skb);
        }
        edge_kernel<<<edge_grid, 256, 0, stream>>>(qb, kb, ssrc, sdst, s_arr);
        float* o = (l == 2) ? out : hbuf;
        agg_kernel<<<agg_grid, 256, 0, stream>>>(s_arr, vb, ssrc, row_off, skb, o);
        if (l < 2) {
            bn_stats_kernel<<<256, 256, 0, stream>>>(hbuf, partials);
            bn_final_kernel<<<1, 128, 0, stream>>>(partials, bnp);
        }
    }
}